// Round 1
// baseline (67.283 us; speedup 1.0000x reference)
//
#include <hip/hip_runtime.h>

// 3x3 median filter, zero padding, B=128, C=1, H=W=512, fp32.
// Each thread produces 4 horizontally-consecutive output pixels (float4).

#define S2(a, b) { float _t = fminf(a, b); b = fmaxf(a, b); a = _t; }

__device__ __forceinline__ float median9(float p0, float p1, float p2,
                                         float p3, float p4, float p5,
                                         float p6, float p7, float p8) {
    // Paeth 19-exchange median-of-9 network; result in p4.
    S2(p1, p2); S2(p4, p5); S2(p7, p8);
    S2(p0, p1); S2(p3, p4); S2(p6, p7);
    S2(p1, p2); S2(p4, p5); S2(p7, p8);
    S2(p0, p3); S2(p5, p8); S2(p4, p7);
    S2(p3, p6); S2(p1, p4); S2(p2, p5);
    S2(p4, p7); S2(p4, p2); S2(p6, p4);
    S2(p4, p2);
    return p4;
}

__global__ __launch_bounds__(256) void median3x3_kernel(
        const float* __restrict__ in, float* __restrict__ out, int total_threads) {
    const int W = 512, H = 512;
    int tid = blockIdx.x * 256 + threadIdx.x;
    if (tid >= total_threads) return;

    int x4   = tid & 127;        // 128 float4-chunks per row
    int rest = tid >> 7;
    int y    = rest & 511;
    int bi   = rest >> 9;        // batch index 0..127
    int x0   = x4 << 2;          // leading column of this thread's 4 pixels

    const float* base = in + (size_t)bi * H * W;

    // v[row][col], col 0 == x0-1 .. col 5 == x0+4, zero-padded out of bounds.
    float v[3][6];
#pragma unroll
    for (int dy = 0; dy < 3; ++dy) {
        int yy = y + dy - 1;
        if (yy >= 0 && yy < H) {                 // wave-uniform branch
            const float* rp = base + (size_t)yy * W + x0;
            float4 m = *reinterpret_cast<const float4*>(rp);
            v[dy][1] = m.x; v[dy][2] = m.y; v[dy][3] = m.z; v[dy][4] = m.w;
            v[dy][0] = (x0 > 0)      ? rp[-1] : 0.0f;
            v[dy][5] = (x0 + 4 < W)  ? rp[4]  : 0.0f;
        } else {
            v[dy][0] = v[dy][1] = v[dy][2] = 0.0f;
            v[dy][3] = v[dy][4] = v[dy][5] = 0.0f;
        }
    }

    float4 o;
    o.x = median9(v[0][0], v[0][1], v[0][2],
                  v[1][0], v[1][1], v[1][2],
                  v[2][0], v[2][1], v[2][2]);
    o.y = median9(v[0][1], v[0][2], v[0][3],
                  v[1][1], v[1][2], v[1][3],
                  v[2][1], v[2][2], v[2][3]);
    o.z = median9(v[0][2], v[0][3], v[0][4],
                  v[1][2], v[1][3], v[1][4],
                  v[2][2], v[2][3], v[2][4]);
    o.w = median9(v[0][3], v[0][4], v[0][5],
                  v[1][3], v[1][4], v[1][5],
                  v[2][3], v[2][4], v[2][5]);

    *reinterpret_cast<float4*>(out + ((size_t)bi * H + y) * W + x0) = o;
}

extern "C" void kernel_launch(void* const* d_in, const int* in_sizes, int n_in,
                              void* d_out, int out_size, void* d_ws, size_t ws_size,
                              hipStream_t stream) {
    const float* x = (const float*)d_in[0];
    float* out = (float*)d_out;

    const int B = 128, H = 512, W = 512;
    int total_threads = B * H * (W / 4);          // 8,388,608
    int blocks = total_threads / 256;             // 32,768

    median3x3_kernel<<<blocks, 256, 0, stream>>>(x, out, total_threads);
}